// Round 1
// baseline (192.979 us; speedup 1.0000x reference)
//
#include <hip/hip_runtime.h>

typedef unsigned short u16;
typedef short short8v __attribute__((ext_vector_type(8)));
typedef float float4v __attribute__((ext_vector_type(4)));
typedef unsigned short ushort4v __attribute__((ext_vector_type(4)));

// ---------------- LDS layout (u16 element offsets) ----------------
// Xs / Ostage : [64][216]                  -> 13824 u16 (27648 B)
// qks         : [8 head][2 part][64][40]   -> 40960 u16 (81920 B); P[64][72] overlays per-head Q,K
// vs          : [8 head][24 d][72 m]       -> 13824 u16 (27648 B)
#define XS_LD   216
#define XS_OFF  0
#define QKS_OFF (64*216)
#define QK_LD   40
#define VS_OFF  (QKS_OFF + 8*2*64*40)
#define VS_LD   72
#define LDS_U16 (VS_OFF + 8*24*72)
#define LDS_BYTES (LDS_U16*2)   // 137216

__device__ __forceinline__ u16 f2bf(float f){
  unsigned u = __builtin_bit_cast(unsigned, f);
  return (u16)((u + 0x7FFFu + ((u >> 16) & 1u)) >> 16);
}

template<int CTRL>
__device__ __forceinline__ float dppf(float v){
  int x = __builtin_bit_cast(int, v);
  int y = __builtin_amdgcn_update_dpp(0, x, CTRL, 0xF, 0xF, true);
  return __builtin_bit_cast(float, y);
}
// reduction over the 16 lanes of a DPP row (lanes with equal lane>>4)
__device__ __forceinline__ float red16max(float v){
  v = fmaxf(v, dppf<0xB1>(v));   // quad_perm [1,0,3,2]  == xor 1
  v = fmaxf(v, dppf<0x4E>(v));   // quad_perm [2,3,0,1]  == xor 2
  v = fmaxf(v, dppf<0x141>(v));  // row_half_mirror      == xor 7
  v = fmaxf(v, dppf<0x140>(v));  // row_mirror           == xor 15
  return v;
}
__device__ __forceinline__ float red16sum(float v){
  v += dppf<0xB1>(v);
  v += dppf<0x4E>(v);
  v += dppf<0x141>(v);
  v += dppf<0x140>(v);
  return v;
}

// ---------------- prep: convert weights to bf16 ----------------
__global__ void prep_convert(const float* __restrict__ qkv_w, const float* __restrict__ proj_w,
                             u16* __restrict__ Wq, u16* __restrict__ Wp){
  int idx = blockIdx.x*blockDim.x + threadIdx.x;
  const int total = 110592 + 36864;
  for (; idx < total; idx += gridDim.x*blockDim.x){
    if (idx < 110592) Wq[idx] = f2bf(qkv_w[idx]);
    else              Wp[idx-110592] = f2bf(proj_w[idx-110592]);
  }
}

__device__ __forceinline__ void lnrelu6(float* v, const float* g, const float* b){
  float mu = (v[0]+v[1]+v[2]+v[3]+v[4]+v[5]) * (1.0f/6.0f);
  float var = 0.f;
  #pragma unroll
  for (int j=0;j<6;++j){ float d = v[j]-mu; var += d*d; }
  var *= (1.0f/6.0f);
  float inv = rsqrtf(var + 1e-5f);
  #pragma unroll
  for (int j=0;j<6;++j) v[j] = fmaxf((v[j]-mu)*inv*g[j] + b[j], 0.f);
}

// ---------------- prep: rel-pos bias table, stored transposed biasT[i*4+h][m][n] ----------------
__global__ void prep_bias(const float* __restrict__ ppw, const float* __restrict__ ppb,
                          const float* __restrict__ ln1g, const float* __restrict__ ln1b,
                          const float* __restrict__ fc1w, const float* __restrict__ fc1b,
                          const float* __restrict__ ln2g, const float* __restrict__ ln2b,
                          const float* __restrict__ fc2w, const float* __restrict__ fc2b,
                          const float* __restrict__ ln3g, const float* __restrict__ ln3b,
                          const float* __restrict__ fc3w, const float* __restrict__ fc3b,
                          float* __restrict__ biasT){
  __shared__ float pos3[2][225][4];
  const int t = threadIdx.x;
  if (t < 225){
    const float dy = (float)(t/15) - 7.0f;
    const float dx = (float)(t%15) - 7.0f;
    for (int i=0;i<2;++i){
      float v[6], y[6];
      #pragma unroll
      for (int j=0;j<6;++j)
        v[j] = dy*ppw[(i*6+j)*2+0] + dx*ppw[(i*6+j)*2+1] + ppb[i*6+j];
      lnrelu6(v, ln1g+i*6, ln1b+i*6);
      #pragma unroll
      for (int j=0;j<6;++j){
        float a = fc1b[i*6+j];
        #pragma unroll
        for (int k=0;k<6;++k) a += v[k]*fc1w[(i*6+j)*6+k];
        y[j] = a;
      }
      lnrelu6(y, ln2g+i*6, ln2b+i*6);
      #pragma unroll
      for (int j=0;j<6;++j){
        float a = fc2b[i*6+j];
        #pragma unroll
        for (int k=0;k<6;++k) a += y[k]*fc2w[(i*6+j)*6+k];
        v[j] = a;
      }
      lnrelu6(v, ln3g+i*6, ln3b+i*6);
      #pragma unroll
      for (int h=0;h<4;++h){
        float a = fc3b[i*4+h];
        #pragma unroll
        for (int k=0;k<6;++k) a += v[k]*fc3w[(i*4+h)*6+k];
        pos3[i][t][h] = a;
      }
    }
  }
  __syncthreads();
  // biasT[(i*4+h)*4096 + m*64 + n] = bias[h][n][m]  (n = query, m = key)
  for (int idx = t; idx < 32768; idx += 256){
    int i  = idx >> 14;
    int hh = (idx >> 12) & 3;
    int m  = (idx >> 6) & 63;
    int n  = idx & 63;
    int tt = ((n>>3)-(m>>3)+7)*15 + ((n&7)-(m&7)+7);
    biasT[idx] = pos3[i][tt][hh];
  }
}

// ---------------- fused main kernel: one 8x8 window per block ----------------
__global__ __launch_bounds__(512, 2) void awa_main(
    const float* __restrict__ x, const u16* __restrict__ Wq,
    const u16* __restrict__ Wp, const float* __restrict__ proj_b,
    const float* __restrict__ biasT, float* __restrict__ out){
  extern __shared__ u16 lds[];
  const int tid  = threadIdx.x;
  const int wave = tid >> 6;
  const int lane = tid & 63;
  const int g    = lane >> 4;
  const int q16  = lane & 15;
  const int bid  = blockIdx.x;
  const int b    = bid >> 10;
  const int win  = bid & 1023;
  const int h1   = win >> 5, w1 = win & 31;
  const size_t xbase = ((size_t)b*65536u + (size_t)(h1*8)*256u + (size_t)(w1*8)) * 192u;
  const short8v z8 = {0,0,0,0,0,0,0,0};

  // ---- Phase 0: stage x window [64 tok][192 ch] -> bf16 LDS ----
  #pragma unroll
  for (int it = 0; it < 6; ++it){
    int fi  = tid + it*512;      // float4 index, 3072 total
    int f   = fi << 2;
    int r   = f / 1536;
    int rem = f - r*1536;
    int s   = rem / 192;
    int c   = rem - s*192;
    float4v xv = *(const float4v*)(x + xbase + (size_t)((r*256 + s)*192 + c));
    ushort4v pk = { f2bf(xv[0]), f2bf(xv[1]), f2bf(xv[2]), f2bf(xv[3]) };
    *(ushort4v*)&lds[XS_OFF + (r*8+s)*XS_LD + c] = pk;
  }
  __syncthreads();

  // ---- Phase 1: C1[64][576] = X @ Wq^T ; scatter into q/k/v LDS layouts ----
  {
    short8v a1[4][6];
    #pragma unroll
    for (int mt=0; mt<4; ++mt)
      #pragma unroll
      for (int kc=0; kc<6; ++kc)
        a1[mt][kc] = *(const short8v*)&lds[XS_OFF + (mt*16+q16)*XS_LD + kc*32 + g*8];

    for (int nt = wave; nt < 36; nt += 8){
      const u16* wb = Wq + (size_t)(nt*16 + q16)*192 + g*8;
      float4v acc[4];
      #pragma unroll
      for (int mt=0;mt<4;++mt) acc[mt] = (float4v){0.f,0.f,0.f,0.f};
      #pragma unroll
      for (int kc=0; kc<6; ++kc){
        short8v bf = *(const short8v*)(wb + kc*32);
        #pragma unroll
        for (int mt=0; mt<4; ++mt)
          acc[mt] = __builtin_amdgcn_mfma_f32_16x16x32_bf16(a1[mt][kc], bf, acc[mt], 0, 0, 0);
      }
      const int j    = nt*16 + q16;      // output channel in [0,576)
      const int part = j / 192;          // 0=q 1=k 2=v
      const int ch   = j - part*192;
      const int ii   = ch / 96;
      const int c2   = ch - ii*96;
      const int hh   = c2 / 24;
      const int d    = c2 - hh*24;
      const int hp   = ii*4 + hh;
      #pragma unroll
      for (int mt=0; mt<4; ++mt){
        #pragma unroll
        for (int r=0; r<4; ++r){
          const int m = mt*16 + g*4 + r;   // token within window
          const u16 val = f2bf(acc[mt][r]);
          if (part < 2) lds[QKS_OFF + ((hp*2+part)*64 + m)*QK_LD + d] = val;
          else          lds[VS_OFF  + (hp*24 + d)*VS_LD + m] = val;   // V stored transposed
        }
      }
    }
  }
  __syncthreads();

  // ---- Phase 2: attention, one head-instance per wave ----
  {
    const int hp = wave;
    const u16* Qb = &lds[QKS_OFF + (hp*2+0)*64*QK_LD];
    const u16* Kb = &lds[QKS_OFF + (hp*2+1)*64*QK_LD];
    short8v qf[4], kf[4];
    #pragma unroll
    for (int mt=0; mt<4; ++mt){
      short8v qv = *(const short8v*)&Qb[(mt*16+q16)*QK_LD + g*8];
      short8v kv = *(const short8v*)&Kb[(mt*16+q16)*QK_LD + g*8];
      qf[mt] = (g==3) ? z8 : qv;   // d=24..31 is padding -> zero in-register
      kf[mt] = (g==3) ? z8 : kv;
    }
    float4v s[4][4];
    #pragma unroll
    for (int mt=0;mt<4;++mt)
      #pragma unroll
      for (int nt=0;nt<4;++nt) s[mt][nt] = (float4v){0.f,0.f,0.f,0.f};
    #pragma unroll
    for (int mt=0;mt<4;++mt)
      #pragma unroll
      for (int nt=0;nt<4;++nt)
        s[mt][nt] = __builtin_amdgcn_mfma_f32_16x16x32_bf16(qf[mt], kf[nt], s[mt][nt], 0, 0, 0);

    // scale + bias (biasT is [hp][m][n] so rows n are contiguous -> float4)
    const float* bt = biasT + hp*4096;
    #pragma unroll
    for (int mt=0;mt<4;++mt)
      #pragma unroll
      for (int nt=0;nt<4;++nt){
        float4v bv = *(const float4v*)&bt[(nt*16+q16)*64 + mt*16 + g*4];
        s[mt][nt] = s[mt][nt]*0.20412414523193154f + bv;
      }

    // softmax over key dim (4 regs x 16 lanes of this DPP row), write P as bf16
    u16* P = &lds[QKS_OFF + hp*2*64*QK_LD];   // overlays this head's (dead) Q,K
    #pragma unroll
    for (int mt=0;mt<4;++mt){
      #pragma unroll
      for (int r=0;r<4;++r){
        float v0 = s[mt][0][r], v1 = s[mt][1][r], v2 = s[mt][2][r], v3 = s[mt][3][r];
        float mx = red16max(fmaxf(fmaxf(v0,v1), fmaxf(v2,v3)));
        float e0 = __expf(v0-mx), e1 = __expf(v1-mx), e2 = __expf(v2-mx), e3 = __expf(v3-mx);
        float inv = 1.0f / red16sum(e0+e1+e2+e3);
        const int n = mt*16 + g*4 + r;
        P[n*72 + q16     ] = f2bf(e0*inv);
        P[n*72 + q16 + 16] = f2bf(e1*inv);
        P[n*72 + q16 + 32] = f2bf(e2*inv);
        P[n*72 + q16 + 48] = f2bf(e3*inv);
      }
    }

    // PV: O[64][24] = P @ V ; V is stored transposed [d][m]
    short8v vf[2][2];
    #pragma unroll
    for (int nt=0;nt<2;++nt){
      const int d  = nt*16 + q16;
      const int dc = (d < 24) ? d : 0;
      #pragma unroll
      for (int kc=0;kc<2;++kc){
        short8v vv = *(const short8v*)&lds[VS_OFF + (hp*24 + dc)*VS_LD + kc*32 + g*8];
        vf[nt][kc] = (d < 24) ? vv : z8;
      }
    }
    float4v o[4][2];
    #pragma unroll
    for (int mt=0;mt<4;++mt)
      #pragma unroll
      for (int nt=0;nt<2;++nt) o[mt][nt] = (float4v){0.f,0.f,0.f,0.f};
    #pragma unroll
    for (int mt=0;mt<4;++mt){
      #pragma unroll
      for (int kc=0;kc<2;++kc){
        short8v pf = *(const short8v*)&P[(mt*16+q16)*72 + kc*32 + g*8];
        #pragma unroll
        for (int nt=0;nt<2;++nt)
          o[mt][nt] = __builtin_amdgcn_mfma_f32_16x16x32_bf16(pf, vf[nt][kc], o[mt][nt], 0, 0, 0);
      }
    }
    // write O into Ostage (reuses Xs region), col base = ii*96 + hh*24
    const int cb = (hp>>2)*96 + (hp&3)*24;
    #pragma unroll
    for (int mt=0;mt<4;++mt){
      #pragma unroll
      for (int nt=0;nt<2;++nt){
        const int d = nt*16 + q16;
        if (d < 24){
          #pragma unroll
          for (int r=0;r<4;++r){
            const int n = mt*16 + g*4 + r;
            lds[XS_OFF + n*XS_LD + cb + d] = f2bf(o[mt][nt][r]);
          }
        }
      }
    }
  }
  __syncthreads();

  // ---- Phase 3: out[64][192] = Ostage @ proj_w^T + proj_b ----
  {
    const int mh = wave & 1, nq = wave >> 1;
    short8v a2[2][6];
    #pragma unroll
    for (int mi=0;mi<2;++mi)
      #pragma unroll
      for (int kc=0;kc<6;++kc)
        a2[mi][kc] = *(const short8v*)&lds[XS_OFF + ((mh*2+mi)*16+q16)*XS_LD + kc*32 + g*8];
    #pragma unroll
    for (int t3=0;t3<3;++t3){
      const int nt = nq + t3*4;
      const int j  = nt*16 + q16;
      const u16* wb = Wp + (size_t)j*192 + g*8;
      float4v pa[2];
      pa[0] = (float4v){0.f,0.f,0.f,0.f};
      pa[1] = (float4v){0.f,0.f,0.f,0.f};
      #pragma unroll
      for (int kc=0;kc<6;++kc){
        short8v bf = *(const short8v*)(wb + kc*32);
        pa[0] = __builtin_amdgcn_mfma_f32_16x16x32_bf16(a2[0][kc], bf, pa[0], 0, 0, 0);
        pa[1] = __builtin_amdgcn_mfma_f32_16x16x32_bf16(a2[1][kc], bf, pa[1], 0, 0, 0);
      }
      const float pb = proj_b[j];
      #pragma unroll
      for (int mi=0;mi<2;++mi){
        #pragma unroll
        for (int r=0;r<4;++r){
          const int n = (mh*2+mi)*16 + g*4 + r;
          const int l = ((h1*8 + (n>>3)) << 8) + w1*8 + (n & 7);
          out[((size_t)b*65536u + (size_t)l)*192u + (size_t)j] = pa[mi][r] + pb;
        }
      }
    }
  }
}

extern "C" void kernel_launch(void* const* d_in, const int* in_sizes, int n_in,
                              void* d_out, int out_size, void* d_ws, size_t ws_size,
                              hipStream_t stream){
  const float* x      = (const float*)d_in[0];
  const float* qkv_w  = (const float*)d_in[1];
  const float* proj_w = (const float*)d_in[2];
  const float* proj_b = (const float*)d_in[3];
  const float* ppw    = (const float*)d_in[4];
  const float* ppb    = (const float*)d_in[5];
  const float* ln1g   = (const float*)d_in[6];
  const float* ln1b   = (const float*)d_in[7];
  const float* fc1w   = (const float*)d_in[8];
  const float* fc1b   = (const float*)d_in[9];
  const float* ln2g   = (const float*)d_in[10];
  const float* ln2b   = (const float*)d_in[11];
  const float* fc2w   = (const float*)d_in[12];
  const float* fc2b   = (const float*)d_in[13];
  const float* ln3g   = (const float*)d_in[14];
  const float* ln3b   = (const float*)d_in[15];
  const float* fc3w   = (const float*)d_in[16];
  const float* fc3b   = (const float*)d_in[17];

  u16*   Wq    = (u16*)d_ws;                       // 110592 bf16
  u16*   Wp    = Wq + 110592;                      //  36864 bf16
  float* biasT = (float*)((char*)d_ws + 294912);   //  32768 f32

  prep_convert<<<144, 256, 0, stream>>>(qkv_w, proj_w, Wq, Wp);
  prep_bias<<<1, 256, 0, stream>>>(ppw, ppb, ln1g, ln1b, fc1w, fc1b,
                                   ln2g, ln2b, fc2w, fc2b, ln3g, ln3b,
                                   fc3w, fc3b, biasT);
  awa_main<<<2048, 512, LDS_BYTES, stream>>>(x, Wq, Wp, proj_b, biasT, (float*)d_out);
}

// Round 2
// 143.089 us; speedup vs baseline: 1.3487x; 1.3487x over previous
//
#include <hip/hip_runtime.h>

typedef unsigned short u16;
typedef short short8v __attribute__((ext_vector_type(8)));
typedef float float4v __attribute__((ext_vector_type(4)));
typedef unsigned short ushort4v __attribute__((ext_vector_type(4)));

// ---------------- LDS layout (u16 element offsets) ----------------
// Region A: C1qk [64 tok][392]  (Q ch 0..191, K ch 192..383, pad)  = 25088 u16
//   overlays: Xs [64][216] (phase 0/1a), P[wave][64][72] (phase 2b, 4*4608),
//             Ostage [64][216] (phase 2c/3)
// Region B: VS [8 hp][24 d][72 m] (V transposed)                   = 13824 u16
#define XLD   216
#define C1LD  392
#define VSLD  72
#define PLD   72
#define VS_OFF (64*C1LD)
#define LDS_U16 (VS_OFF + 8*24*VSLD)
#define LDS_BYTES (LDS_U16*2)   // 77824 -> 2 blocks/CU

__device__ __forceinline__ u16 f2bf(float f){
  unsigned u = __builtin_bit_cast(unsigned, f);
  return (u16)((u + 0x7FFFu + ((u >> 16) & 1u)) >> 16);
}

// ---------------- prep: convert weights to bf16 ----------------
__global__ void prep_convert(const float* __restrict__ qkv_w, const float* __restrict__ proj_w,
                             u16* __restrict__ Wq, u16* __restrict__ Wp){
  int idx = blockIdx.x*blockDim.x + threadIdx.x;
  const int total = 110592 + 36864;
  for (; idx < total; idx += gridDim.x*blockDim.x){
    if (idx < 110592) Wq[idx] = f2bf(qkv_w[idx]);
    else              Wp[idx-110592] = f2bf(proj_w[idx-110592]);
  }
}

__device__ __forceinline__ void lnrelu6(float* v, const float* g, const float* b){
  float mu = (v[0]+v[1]+v[2]+v[3]+v[4]+v[5]) * (1.0f/6.0f);
  float var = 0.f;
  #pragma unroll
  for (int j=0;j<6;++j){ float d = v[j]-mu; var += d*d; }
  var *= (1.0f/6.0f);
  float inv = rsqrtf(var + 1e-5f);
  #pragma unroll
  for (int j=0;j<6;++j) v[j] = fmaxf((v[j]-mu)*inv*g[j] + b[j], 0.f);
}

// ---------------- prep: rel-pos bias table, biasT[(i*4+h)][n=query][m=key] ----------------
__global__ void prep_bias(const float* __restrict__ ppw, const float* __restrict__ ppb,
                          const float* __restrict__ ln1g, const float* __restrict__ ln1b,
                          const float* __restrict__ fc1w, const float* __restrict__ fc1b,
                          const float* __restrict__ ln2g, const float* __restrict__ ln2b,
                          const float* __restrict__ fc2w, const float* __restrict__ fc2b,
                          const float* __restrict__ ln3g, const float* __restrict__ ln3b,
                          const float* __restrict__ fc3w, const float* __restrict__ fc3b,
                          float* __restrict__ biasT){
  __shared__ float pos3[2][225][4];
  const int t = threadIdx.x;
  if (t < 225){
    const float dy = (float)(t/15) - 7.0f;
    const float dx = (float)(t%15) - 7.0f;
    for (int i=0;i<2;++i){
      float v[6], y[6];
      #pragma unroll
      for (int j=0;j<6;++j)
        v[j] = dy*ppw[(i*6+j)*2+0] + dx*ppw[(i*6+j)*2+1] + ppb[i*6+j];
      lnrelu6(v, ln1g+i*6, ln1b+i*6);
      #pragma unroll
      for (int j=0;j<6;++j){
        float a = fc1b[i*6+j];
        #pragma unroll
        for (int k=0;k<6;++k) a += v[k]*fc1w[(i*6+j)*6+k];
        y[j] = a;
      }
      lnrelu6(y, ln2g+i*6, ln2b+i*6);
      #pragma unroll
      for (int j=0;j<6;++j){
        float a = fc2b[i*6+j];
        #pragma unroll
        for (int k=0;k<6;++k) a += y[k]*fc2w[(i*6+j)*6+k];
        v[j] = a;
      }
      lnrelu6(v, ln3g+i*6, ln3b+i*6);
      #pragma unroll
      for (int h=0;h<4;++h){
        float a = fc3b[i*4+h];
        #pragma unroll
        for (int k=0;k<6;++k) a += v[k]*fc3w[(i*4+h)*6+k];
        pos3[i][t][h] = a;
      }
    }
  }
  __syncthreads();
  // biasT[(i*4+h)*4096 + n*64 + m] = bias[h][n(query)][m(key)]
  for (int idx = t; idx < 32768; idx += 256){
    int i  = idx >> 14;
    int hh = (idx >> 12) & 3;
    int n  = (idx >> 6) & 63;
    int m  = idx & 63;
    int tt = (((n>>3)-(m>>3)+7)*15) + ((n&7)-(m&7)+7);
    biasT[idx] = pos3[i][tt][hh];
  }
}

// ---------------- fused main kernel: one 8x8 window per block, 4 waves ----------------
__global__ __launch_bounds__(256, 2) void awa_main(
    const float* __restrict__ x, const u16* __restrict__ Wq,
    const u16* __restrict__ Wp, const float* __restrict__ proj_b,
    const float* __restrict__ biasT, float* __restrict__ out){
  extern __shared__ u16 lds[];
  const int tid  = threadIdx.x;
  const int wave = tid >> 6;
  const int lane = tid & 63;
  const int g    = lane >> 4;
  const int q16  = lane & 15;
  const int bid  = blockIdx.x;
  const int b    = bid >> 10;
  const int win  = bid & 1023;
  const int h1   = win >> 5, w1 = win & 31;
  const size_t xbase = ((size_t)b*65536u + (size_t)(h1*8)*256u + (size_t)(w1*8)) * 192u;
  const short8v z8 = {0,0,0,0,0,0,0,0};

  // ---- Phase 0: stage x window [64 tok][192 ch] -> bf16 Xs ----
  #pragma unroll
  for (int it = 0; it < 12; ++it){
    int fi  = tid + it*256;      // float4 index, 3072 total
    int f   = fi << 2;
    int rr  = f / 1536;
    int rem = f - rr*1536;
    int ss  = rem / 192;
    int cc  = rem - ss*192;
    float4v xv = *(const float4v*)(x + xbase + (size_t)((rr*256 + ss)*192 + cc));
    ushort4v pk = { f2bf(xv[0]), f2bf(xv[1]), f2bf(xv[2]), f2bf(xv[3]) };
    *(ushort4v*)&lds[(rr*8+ss)*XLD + cc] = pk;
  }
  __syncthreads();

  // ---- Phase 1a: X fragments to registers; prefetch first W tile ----
  short8v xf[4][6];
  #pragma unroll
  for (int mt=0; mt<4; ++mt)
    #pragma unroll
    for (int kc=0; kc<6; ++kc)
      xf[mt][kc] = *(const short8v*)&lds[(mt*16+q16)*XLD + kc*32 + g*8];
  short8v wf[2][6];
  {
    const u16* wb = Wq + (size_t)(wave*16 + q16)*192 + g*8;
    #pragma unroll
    for (int kc=0;kc<6;++kc) wf[0][kc] = *(const short8v*)(wb + kc*32);
  }
  __syncthreads();   // Xs dead -> C1 writes allowed

  // ---- Phase 1b: C1 = X @ Wq^T, 9 tiles/wave, double-buffered W ----
  #pragma unroll
  for (int t=0; t<9; ++t){
    const int nt = wave + t*4;
    if (t < 8){
      const u16* wb = Wq + (size_t)((nt+4)*16 + q16)*192 + g*8;
      #pragma unroll
      for (int kc=0;kc<6;++kc) wf[(t+1)&1][kc] = *(const short8v*)(wb + kc*32);
    }
    float4v acc[4];
    #pragma unroll
    for (int mt=0;mt<4;++mt) acc[mt] = (float4v){0.f,0.f,0.f,0.f};
    if (t < 6){
      // q/k tiles: transposed orientation -> lane holds 4 consecutive channels
      #pragma unroll
      for (int kc=0; kc<6; ++kc)
        #pragma unroll
        for (int mt=0; mt<4; ++mt)
          acc[mt] = __builtin_amdgcn_mfma_f32_16x16x32_bf16(wf[t&1][kc], xf[mt][kc], acc[mt], 0,0,0);
      const int cb = nt*16 + g*4;
      #pragma unroll
      for (int mt=0; mt<4; ++mt){
        ushort4v pk = { f2bf(acc[mt][0]), f2bf(acc[mt][1]), f2bf(acc[mt][2]), f2bf(acc[mt][3]) };
        *(ushort4v*)&lds[(mt*16+q16)*C1LD + cb] = pk;
      }
    } else {
      // v tiles: normal orientation -> lane holds 4 consecutive tokens, store V^T
      #pragma unroll
      for (int kc=0; kc<6; ++kc)
        #pragma unroll
        for (int mt=0; mt<4; ++mt)
          acc[mt] = __builtin_amdgcn_mfma_f32_16x16x32_bf16(xf[mt][kc], wf[t&1][kc], acc[mt], 0,0,0);
      const int jj  = nt*16 + q16 - 384;       // v channel 0..191
      const int ii2 = (jj >= 96) ? 1 : 0;
      const int c2  = jj - ii2*96;
      const int hh2 = c2 / 24;
      const int d   = c2 - hh2*24;
      const int vb  = VS_OFF + ((ii2*4 + hh2)*24 + d)*VSLD + g*4;
      #pragma unroll
      for (int mt=0; mt<4; ++mt){
        ushort4v pk = { f2bf(acc[mt][0]), f2bf(acc[mt][1]), f2bf(acc[mt][2]), f2bf(acc[mt][3]) };
        *(ushort4v*)&lds[vb + mt*16] = pk;
      }
    }
  }
  __syncthreads();

  // ---- Phase 2a: load Q,K fragments for both heads (hp = wave, wave+4) ----
  short8v qf[2][4], kf[2][4];
  #pragma unroll
  for (int h=0; h<2; ++h){
    const int qb = h*96 + wave*24;
    #pragma unroll
    for (int mt=0; mt<4; ++mt){
      short8v a = *(const short8v*)&lds[(mt*16+q16)*C1LD + qb + g*8];
      short8v c = *(const short8v*)&lds[(mt*16+q16)*C1LD + 192 + qb + g*8];
      qf[h][mt] = (g==3) ? z8 : a;   // d=24..31 pad -> zero in-register
      kf[h][mt] = (g==3) ? z8 : c;
    }
  }
  __syncthreads();   // C1 dead -> per-wave P region usable

  // ---- Phase 2b: per head: QK^T -> softmax -> P -> PV ----
  u16* P = &lds[wave*4608];   // per-wave private [64][72]
  float4v oo[2][2][4];
  #pragma unroll
  for (int h=0; h<2; ++h){
    const int hp = h*4 + wave;
    // S^T[key][tok] = K Q^T (swapped operands: lane holds 4 consecutive keys)
    float4v s[4][4];   // [kt][mt]
    #pragma unroll
    for (int kt=0;kt<4;++kt)
      #pragma unroll
      for (int mt=0;mt<4;++mt)
        s[kt][mt] = (float4v){0.f,0.f,0.f,0.f};
    #pragma unroll
    for (int kt=0;kt<4;++kt)
      #pragma unroll
      for (int mt=0;mt<4;++mt)
        s[kt][mt] = __builtin_amdgcn_mfma_f32_16x16x32_bf16(kf[h][kt], qf[h][mt], s[kt][mt], 0,0,0);
    // scale + bias[tok][key] (float4 along key)
    const float* bt = biasT + hp*4096;
    #pragma unroll
    for (int kt=0;kt<4;++kt)
      #pragma unroll
      for (int mt=0;mt<4;++mt){
        float4v bv = *(const float4v*)&bt[(mt*16+q16)*64 + kt*16 + g*4];
        s[kt][mt] = s[kt][mt]*0.20412414523193154f + bv;
      }
    // softmax over key: 16 in-lane values + cross-lane over the 4 g-groups
    #pragma unroll
    for (int mt=0;mt<4;++mt){
      float mx = s[0][mt][0];
      #pragma unroll
      for (int kt=0;kt<4;++kt)
        #pragma unroll
        for (int r=0;r<4;++r) mx = fmaxf(mx, s[kt][mt][r]);
      mx = fmaxf(mx, __shfl_xor(mx, 16));
      mx = fmaxf(mx, __shfl_xor(mx, 32));
      float e[4][4]; float sum = 0.f;
      #pragma unroll
      for (int kt=0;kt<4;++kt)
        #pragma unroll
        for (int r=0;r<4;++r){ float t2 = __expf(s[kt][mt][r]-mx); e[kt][r] = t2; sum += t2; }
      sum += __shfl_xor(sum, 16);
      sum += __shfl_xor(sum, 32);
      const float inv = 1.0f / sum;
      #pragma unroll
      for (int kt=0;kt<4;++kt){
        ushort4v pk = { f2bf(e[kt][0]*inv), f2bf(e[kt][1]*inv), f2bf(e[kt][2]*inv), f2bf(e[kt][3]*inv) };
        *(ushort4v*)&P[(mt*16+q16)*PLD + kt*16 + g*4] = pk;
      }
    }
    // V^T fragments (rows d, zero d>=24)
    short8v vf[2][2];
    #pragma unroll
    for (int dt=0;dt<2;++dt){
      const int d  = dt*16 + q16;
      const int dc = (d < 24) ? d : 0;
      #pragma unroll
      for (int kc=0;kc<2;++kc){
        short8v vv = *(const short8v*)&lds[VS_OFF + (hp*24 + dc)*VSLD + kc*32 + g*8];
        vf[dt][kc] = (d < 24) ? vv : z8;
      }
    }
    // O^T[d][tok] = V^T P^T : lane ends with 4 consecutive d per tok
    #pragma unroll
    for (int dt=0;dt<2;++dt)
      #pragma unroll
      for (int mt=0;mt<4;++mt) oo[h][dt][mt] = (float4v){0.f,0.f,0.f,0.f};
    #pragma unroll
    for (int mt=0;mt<4;++mt){
      #pragma unroll
      for (int kc=0;kc<2;++kc){
        short8v pf = *(const short8v*)&P[(mt*16+q16)*PLD + kc*32 + g*8];
        #pragma unroll
        for (int dt=0;dt<2;++dt)
          oo[h][dt][mt] = __builtin_amdgcn_mfma_f32_16x16x32_bf16(vf[dt][kc], pf, oo[h][dt][mt], 0,0,0);
      }
    }
  }
  __syncthreads();   // all waves done reading their P

  // ---- Phase 2c: O -> Ostage (overlays C1/P region), packed b64 ----
  #pragma unroll
  for (int h=0; h<2; ++h){
    const int cb = h*96 + wave*24;
    #pragma unroll
    for (int dt=0; dt<2; ++dt){
      if (dt==0 || g<2){    // d0 = dt*16+g*4 must be < 24
        #pragma unroll
        for (int mt=0; mt<4; ++mt){
          ushort4v pk = { f2bf(oo[h][dt][mt][0]), f2bf(oo[h][dt][mt][1]),
                          f2bf(oo[h][dt][mt][2]), f2bf(oo[h][dt][mt][3]) };
          *(ushort4v*)&lds[(mt*16+q16)*XLD + cb + dt*16 + g*4] = pk;
        }
      }
    }
  }
  // prefetch first proj weight tile while waiting at the barrier
  short8v wp[2][6];
  {
    const u16* wb = Wp + (size_t)(wave*16 + q16)*192 + g*8;
    #pragma unroll
    for (int kc=0;kc<6;++kc) wp[0][kc] = *(const short8v*)(wb + kc*32);
  }
  __syncthreads();

  // ---- Phase 3: out = Ostage @ proj_w^T + b, transposed orient -> dwordx4 stores ----
  short8v a2[4][6];
  #pragma unroll
  for (int mt=0; mt<4; ++mt)
    #pragma unroll
    for (int kc=0; kc<6; ++kc)
      a2[mt][kc] = *(const short8v*)&lds[(mt*16+q16)*XLD + kc*32 + g*8];
  #pragma unroll
  for (int t=0; t<3; ++t){
    const int nt = wave + t*4;
    if (t < 2){
      const u16* wb = Wp + (size_t)((nt+4)*16 + q16)*192 + g*8;
      #pragma unroll
      for (int kc=0;kc<6;++kc) wp[(t+1)&1][kc] = *(const short8v*)(wb + kc*32);
    }
    float4v acc[4];
    #pragma unroll
    for (int mt=0;mt<4;++mt) acc[mt] = (float4v){0.f,0.f,0.f,0.f};
    #pragma unroll
    for (int kc=0; kc<6; ++kc)
      #pragma unroll
      for (int mt=0; mt<4; ++mt)
        acc[mt] = __builtin_amdgcn_mfma_f32_16x16x32_bf16(wp[t&1][kc], a2[mt][kc], acc[mt], 0,0,0);
    const int j0 = nt*16 + g*4;
    const float4v pb = *(const float4v*)(proj_b + j0);
    #pragma unroll
    for (int mt=0; mt<4; ++mt){
      const int tok = mt*16 + q16;
      const int l = ((h1*8 + (tok>>3)) << 8) + w1*8 + (tok & 7);
      float4v res = acc[mt] + pb;
      *(float4v*)(out + ((size_t)b*65536u + (size_t)l)*192u + j0) = res;
    }
  }
}

extern "C" void kernel_launch(void* const* d_in, const int* in_sizes, int n_in,
                              void* d_out, int out_size, void* d_ws, size_t ws_size,
                              hipStream_t stream){
  const float* x      = (const float*)d_in[0];
  const float* qkv_w  = (const float*)d_in[1];
  const float* proj_w = (const float*)d_in[2];
  const float* proj_b = (const float*)d_in[3];
  const float* ppw    = (const float*)d_in[4];
  const float* ppb    = (const float*)d_in[5];
  const float* ln1g   = (const float*)d_in[6];
  const float* ln1b   = (const float*)d_in[7];
  const float* fc1w   = (const float*)d_in[8];
  const float* fc1b   = (const float*)d_in[9];
  const float* ln2g   = (const float*)d_in[10];
  const float* ln2b   = (const float*)d_in[11];
  const float* fc2w   = (const float*)d_in[12];
  const float* fc2b   = (const float*)d_in[13];
  const float* ln3g   = (const float*)d_in[14];
  const float* ln3b   = (const float*)d_in[15];
  const float* fc3w   = (const float*)d_in[16];
  const float* fc3b   = (const float*)d_in[17];

  u16*   Wq    = (u16*)d_ws;                       // 110592 bf16
  u16*   Wp    = Wq + 110592;                      //  36864 bf16
  float* biasT = (float*)((char*)d_ws + 294912);   //  32768 f32

  prep_convert<<<144, 256, 0, stream>>>(qkv_w, proj_w, Wq, Wp);
  prep_bias<<<1, 256, 0, stream>>>(ppw, ppb, ln1g, ln1b, fc1w, fc1b,
                                   ln2g, ln2b, fc2w, fc2b, ln3g, ln3b,
                                   fc3w, fc3b, biasT);
  awa_main<<<2048, 256, LDS_BYTES, stream>>>(x, Wq, Wp, proj_b, biasT, (float*)d_out);
}